// Round 8
// baseline (572.621 us; speedup 1.0000x reference)
//
#include <hip/hip_runtime.h>

// x[B=16, C=64, H=256, W=256] fp32.
//   e[b,h,w]     = exp(sqrt(sum_c x^2) - 8)      (shift exact in the ratio)
//   den[b,w]     = sum_h e
//   comp[b,c,w]  = sum_h x*e / (den*(1+1e-8))
//   out[b,c,h,w] = comp broadcast over h
//
// Established R1-R7: dur = ~304 µs const (unconditional poison fills + overhead)
// + kernel_total. R2 kernels ~153 µs vs ~92 µs traffic floor; per-phase
// rewrites (occupancy/pipeline/no-barrier/fusion/store-path) all neutral ->
// each phase alone is issue-limited ~5 TB/s; slack = phases run SEQUENTIALLY
// (read-heavy pass1, then write-heavy pass2).
// R8: single producer-consumer kernel. Block (b,hc): pass1 work -> release
// atomicAdd(done[b]) -> spin until done[b]==32 -> pass2 for c=2hc,2hc+1.
// All 32 same-b blocks co-resident (512 blk x 8 waves = 4096 <= 8192 waves)
// => deadlock-free with zero dispatch-order assumptions (G16). Overlap: batch
// b's out-writes run while later batches' x-reads stream -> both HBM
// directions active. Flags zeroed via hipMemsetAsync (graph-capturable).

constexpr int B = 16, C = 64, H = 256, W = 256, W4 = 64;
constexpr int HC = 32;          // h-chunks per image
constexpr int HPC = H / HC;     // 8 h per chunk
constexpr float KSUB = 8.0f;

typedef float nfloat4 __attribute__((ext_vector_type(4)));

__device__ __forceinline__ float4 f4add(float4 a, float4 b) {
    return make_float4(a.x + b.x, a.y + b.y, a.z + b.z, a.w + b.w);
}

// 512 blocks x 512 thr; block = (b, hc).
// Phase A thread = (cg in [0,8), w4); phase B thread = (hg in [0,8), w4).
__global__ __launch_bounds__(512, 4) void k_main(const float* __restrict__ x,
                                                 float4* __restrict__ pcomp,  // [B][HC][C][W4]
                                                 float4* __restrict__ pden,   // [B][HC][W4]
                                                 int* __restrict__ done,      // [B]
                                                 float* __restrict__ out) {
    __shared__ float4 red[2][8][64];   // phase A: double-buffer; phase B: redc/redd
    int blk = blockIdx.x;
    int b = blk >> 5, hc = blk & 31;
    int t = threadIdx.x, cg = t >> 6, w4 = t & 63;
    int h0 = hc * HPC;

    // ---------------- Phase A: R2 pass1, verbatim ----------------
    {
        const float4* xb = (const float4*)x + ((size_t)(b * C + cg * 8) * H + h0) * W4 + w4;
        float4 acc[8];
#pragma unroll
        for (int j = 0; j < 8; ++j) acc[j] = make_float4(0.f, 0.f, 0.f, 0.f);
        float4 dacc = make_float4(0.f, 0.f, 0.f, 0.f);

        for (int hh = 0; hh < HPC; ++hh) {
            float4 xv[8];
            float4 ps = make_float4(0.f, 0.f, 0.f, 0.f);
#pragma unroll
            for (int j = 0; j < 8; ++j) {
                xv[j] = xb[(size_t)j * H * W4 + (size_t)hh * W4];   // coalesced 16B/lane
                ps.x += xv[j].x * xv[j].x; ps.y += xv[j].y * xv[j].y;
                ps.z += xv[j].z * xv[j].z; ps.w += xv[j].w * xv[j].w;
            }
            red[hh & 1][cg][w4] = ps;
            __syncthreads();
            float4 s = make_float4(0.f, 0.f, 0.f, 0.f);
#pragma unroll
            for (int g = 0; g < 8; ++g) s = f4add(s, red[hh & 1][g][w4]);
            float4 e = make_float4(__expf(sqrtf(s.x) - KSUB), __expf(sqrtf(s.y) - KSUB),
                                   __expf(sqrtf(s.z) - KSUB), __expf(sqrtf(s.w) - KSUB));
            if (cg == 0) dacc = f4add(dacc, e);
#pragma unroll
            for (int j = 0; j < 8; ++j) {
                acc[j].x += xv[j].x * e.x; acc[j].y += xv[j].y * e.y;
                acc[j].z += xv[j].z * e.z; acc[j].w += xv[j].w * e.w;
            }
        }

        size_t pc = ((size_t)(b * HC + hc) * C + cg * 8) * W4 + w4;
#pragma unroll
        for (int j = 0; j < 8; ++j)
            pcomp[pc + (size_t)j * W4] = acc[j];
        if (cg == 0)
            pden[(size_t)(b * HC + hc) * W4 + w4] = dacc;
    }

    // ---------------- Publish + wait for this batch ----------------
    __syncthreads();                       // all waves' stores retired (vmcnt drain)
    if (t == 0) {
        __threadfence();                   // L2 writeback to coherence point
        __hip_atomic_fetch_add(&done[b], 1, __ATOMIC_RELEASE, __HIP_MEMORY_SCOPE_AGENT);
        while (__hip_atomic_load(&done[b], __ATOMIC_ACQUIRE, __HIP_MEMORY_SCOPE_AGENT) < HC)
            __builtin_amdgcn_s_sleep(8);
        __threadfence();                   // acquire: invalidate stale lines
    }
    __syncthreads();                       // broadcast "batch ready" to all waves

    // ---------------- Phase B: pass2 for c = 2*hc, 2*hc+1 ----------------
    int hg = t >> 6;                       // 8 groups x 4 hc each
    float4 sd = make_float4(0.f, 0.f, 0.f, 0.f);
#pragma unroll
    for (int k = 0; k < 4; ++k)
        sd = f4add(sd, pden[(size_t)(b * HC + hg * 4 + k) * W4 + w4]);
    red[1][hg][w4] = sd;                   // redd (never overwritten below)

#pragma unroll
    for (int ci = 0; ci < 2; ++ci) {
        int cc = hc * 2 + ci;
        float4 sc = make_float4(0.f, 0.f, 0.f, 0.f);
#pragma unroll
        for (int k = 0; k < 4; ++k)
            sc = f4add(sc, pcomp[((size_t)(b * HC + hg * 4 + k) * C + cc) * W4 + w4]);
        red[0][hg][w4] = sc;
        __syncthreads();
        float4 Cs = make_float4(0.f, 0.f, 0.f, 0.f), Ds = Cs;
#pragma unroll
        for (int g = 0; g < 8; ++g) {
            Cs = f4add(Cs, red[0][g][w4]);
            Ds = f4add(Ds, red[1][g][w4]);
        }
        __syncthreads();                   // reads done before next ci overwrites red[0]
        nfloat4 f = { Cs.x / (Ds.x * (1.0f + 1e-8f)),
                      Cs.y / (Ds.y * (1.0f + 1e-8f)),
                      Cs.z / (Ds.z * (1.0f + 1e-8f)),
                      Cs.w / (Ds.w * (1.0f + 1e-8f)) };
        nfloat4* op = (nfloat4*)out + (size_t)(b * C + cc) * H * W4;
#pragma unroll
        for (int i = 0; i < 32; ++i)       // 16384 float4 / 512 thr
            __builtin_nontemporal_store(f, op + (size_t)i * 512 + t);
    }
}

extern "C" void kernel_launch(void* const* d_in, const int* in_sizes, int n_in,
                              void* d_out, int out_size, void* d_ws, size_t ws_size,
                              hipStream_t stream) {
    const float* x = (const float*)d_in[0];
    float* out = (float*)d_out;
    float4* pcomp = (float4*)d_ws;                                // 32 MB
    float4* pden  = pcomp + (size_t)B * HC * C * W4;              // 512 KB
    int*    done  = (int*)(pden + (size_t)B * HC * W4);           // 64 B flags

    hipMemsetAsync(done, 0, B * sizeof(int), stream);             // un-poison flags
    k_main<<<B * HC, 512, 0, stream>>>(x, pcomp, pden, done, out);
}

// Round 9
// 484.016 us; speedup vs baseline: 1.1831x; 1.1831x over previous
//
#include <hip/hip_runtime.h>

// x[B=16, C=64, H=256, W=256] fp32 — FUSED single kernel, R6 geometry.
//   e[b,h,w]     = exp(sqrt(sum_c x^2) - 8)      (shift exact in the ratio)
//   den[b,w]     = sum_h e
//   comp[b,c,w]  = sum_h x*e / (den*(1+1e-8))
//   out[b,c,h,w] = comp broadcast over h
//
// Established: dur = K(~294 µs fill+overhead) + kernel time. Two-pass R2 ~163 µs.
// R6 fused measured 186 µs @ 2.2 TB/s, grid=256 -> 1 block/CU, occupancy 16% —
// grid-starved, not geometry-broken (FETCH 132MB = no overfetch; L3 retains
// half of x across iterations). R8 spin-sync overlap: falsified (287 µs).
// R9 = R6 with ONE change: 1024 threads/block -> 16 waves/CU (2x latency
// hiding), k-loop 16->8. Same (b,wo) tiling, same pair-swizzle (sibling block
// sharing each 128B line sits 128 apart in blockIdx -> same XCD), same lane
// map (hbit, c8, w2). LDS 68KB, 1 block/CU.

constexpr int B = 16, C = 64, H = 256, W = 256, W4 = 64;
constexpr float KSUB = 8.0f;

__device__ __forceinline__ float4 f4add(float4 a, float4 b) {
    return make_float4(a.x + b.x, a.y + b.y, a.z + b.z, a.w + b.w);
}

__global__ __launch_bounds__(1024, 1) void k_fused(const float* __restrict__ x,
                                                   float4* __restrict__ out4) {
    __shared__ float4 part[16][64][4];  // [wave][c][w2]  64 KB
    __shared__ float4 denp[16][4];      // [wave][w2]      1 KB
    __shared__ float4 fin[64][4];       // [c][w2]         4 KB

    int blk = blockIdx.x;
    int m = blk >> 7, g = blk & 127;          // pair-swizzle
    int b = g >> 3, wo = ((g & 7) << 1) | m;  // (b,wo),(b,wo^1) same XCD
    int t = threadIdx.x;
    int wave = t >> 6, lane = t & 63;         // 16 waves
    int hbit = lane >> 5;                     // bit 5
    int c8   = (lane >> 2) & 7;               // bits 2..4
    int w2   = lane & 3;                      // bits 0..1
    int w4   = wo * 4 + w2;

    const float4* xb = (const float4*)x + ((size_t)(b * C + c8) * H) * W4 + w4;
    constexpr size_t CSTR = (size_t)8 * H * W4;    // 8-channel stride (float4)

    float4 acc[8];
#pragma unroll
    for (int j = 0; j < 8; ++j) acc[j] = make_float4(0.f, 0.f, 0.f, 0.f);
    float4 dacc = make_float4(0.f, 0.f, 0.f, 0.f);

    for (int k = 0; k < 8; ++k) {
        int h = wave * 2 + hbit + 32 * k;          // 16 waves x 2 hbit x 8 k = 256
        float4 xv[8];
#pragma unroll
        for (int j = 0; j < 8; ++j)
            xv[j] = xb[(size_t)j * CSTR + (size_t)h * W4];   // 64B segs, L2-paired
        float4 ps = make_float4(0.f, 0.f, 0.f, 0.f);
#pragma unroll
        for (int j = 0; j < 8; ++j) {
            ps.x += xv[j].x * xv[j].x; ps.y += xv[j].y * xv[j].y;
            ps.z += xv[j].z * xv[j].z; ps.w += xv[j].w * xv[j].w;
        }
        // butterfly over c8 (lane bits 2..4): full 64-channel sumsq, no LDS
#pragma unroll
        for (int msk = 4; msk <= 16; msk <<= 1) {
            ps.x += __shfl_xor(ps.x, msk);
            ps.y += __shfl_xor(ps.y, msk);
            ps.z += __shfl_xor(ps.z, msk);
            ps.w += __shfl_xor(ps.w, msk);
        }
        float4 e = make_float4(__expf(sqrtf(ps.x) - KSUB), __expf(sqrtf(ps.y) - KSUB),
                               __expf(sqrtf(ps.z) - KSUB), __expf(sqrtf(ps.w) - KSUB));
        dacc = f4add(dacc, e);
#pragma unroll
        for (int j = 0; j < 8; ++j) {
            acc[j].x += xv[j].x * e.x; acc[j].y += xv[j].y * e.y;
            acc[j].z += xv[j].z * e.z; acc[j].w += xv[j].w * e.w;
        }
    }

    // fold hbit (mask 32): both h-halves of the wave into one partial
#pragma unroll
    for (int j = 0; j < 8; ++j) {
        acc[j].x += __shfl_xor(acc[j].x, 32); acc[j].y += __shfl_xor(acc[j].y, 32);
        acc[j].z += __shfl_xor(acc[j].z, 32); acc[j].w += __shfl_xor(acc[j].w, 32);
    }
    dacc.x += __shfl_xor(dacc.x, 32); dacc.y += __shfl_xor(dacc.y, 32);
    dacc.z += __shfl_xor(dacc.z, 32); dacc.w += __shfl_xor(dacc.w, 32);

    if (hbit == 0) {
#pragma unroll
        for (int j = 0; j < 8; ++j)
            part[wave][c8 + 8 * j][w2] = acc[j];
        if (c8 == 0) denp[wave][w2] = dacc;
    }
    __syncthreads();

    if (t < 256) {                  // (c, w2) final reduce over 16 waves
        int c = t >> 2, wq = t & 3;
        float4 Cs = make_float4(0.f, 0.f, 0.f, 0.f), Ds = Cs;
#pragma unroll
        for (int wv = 0; wv < 16; ++wv) {
            Cs = f4add(Cs, part[wv][c][wq]);
            Ds = f4add(Ds, denp[wv][wq]);
        }
        fin[c][wq] = make_float4(Cs.x / (Ds.x * (1.0f + 1e-8f)),
                                 Cs.y / (Ds.y * (1.0f + 1e-8f)),
                                 Cs.z / (Ds.z * (1.0f + 1e-8f)),
                                 Cs.w / (Ds.w * (1.0f + 1e-8f)));
    }
    __syncthreads();

    // broadcast write: thread = (h = t>>2, wq = t&3); one store per (c) per thread
    int h = t >> 2, wq = t & 3;                      // h in [0,256), exact cover
    float4* ob = out4 + (size_t)b * C * H * W4 + (size_t)wo * 4 + wq;
    for (int c = 0; c < C; ++c) {
        float4 f = fin[c][wq];                       // LDS broadcast read
        ob[(size_t)c * H * W4 + (size_t)h * W4] = f; // 64B segs, L2-paired
    }
}

extern "C" void kernel_launch(void* const* d_in, const int* in_sizes, int n_in,
                              void* d_out, int out_size, void* d_ws, size_t ws_size,
                              hipStream_t stream) {
    const float* x = (const float*)d_in[0];
    float4* out4 = (float4*)d_out;
    (void)d_ws; (void)ws_size;   // no workspace needed (poison is unconditional)

    k_fused<<<B * 16, 1024, 0, stream>>>(x, out4);
}